// Round 6
// baseline (2045.269 us; speedup 1.0000x reference)
//
#include <hip/hip_runtime.h>

#define IDIM 512
#define MIXD 32
#define HID 96
#define BB 256
#define TT 512

typedef float f32x2 __attribute__((ext_vector_type(2)));
typedef float f32x4 __attribute__((ext_vector_type(4)));

// v_exp_f32: D = 2^S0
#define EXP2(x) __builtin_amdgcn_exp2f(x)

// DPP row_shl:N add on the VALU pipe (not the shared LDS pipe).
// dpp_ctrl must be an ICE at the call site -> template parameter.
template <int CTRL>
__device__ __forceinline__ float dpp_shl_add(float x) {
    int m = __builtin_amdgcn_update_dpp(0, __float_as_int(x), CTRL, 0xf, 0xf, true);
    return x + __int_as_float(m);
}
// Reduce 8 consecutive lanes (octet) into the octet's lane 0.
__device__ __forceinline__ float octet_reduce_lane0(float x) {
    x = dpp_shl_add<0x104>(x);   // row_shl:4
    x = dpp_shl_add<0x102>(x);   // row_shl:2
    x = dpp_shl_add<0x101>(x);   // row_shl:1
    return x;
}

// ---------------- K1: z = x @ W_mix^T -----------------------------------
// 268 MB read, memory-bound. W_mix (64 KB) staged in LDS; reads of W are
// 8-way lane-broadcast + all-32-bank covering (conflict-free). x loads are
// coalesced: octet s=0..7 reads 8 consecutive float4 of one row. Per-lane
// partials (8-way k-split) reduced to octet lane 0 via DPP.
__global__ __launch_bounds__(256) void k_mix(const float* __restrict__ x,
                                             const float* __restrict__ Wmix,
                                             float* __restrict__ z) {
    __shared__ __align__(16) float sw[MIXD][IDIM];   // 64 KB
    const int tid = threadIdx.x;
    {   // stage W coalesced: 4096 float4 / 256 threads = 16 iters
        const f32x4* wg = (const f32x4*)Wmix;
        f32x4* wl = (f32x4*)&sw[0][0];
        #pragma unroll
        for (int i = 0; i < 16; ++i) wl[tid + 256 * i] = wg[tid + 256 * i];
    }
    __syncthreads();

    const int w  = tid >> 6, l = tid & 63;
    const int s  = l & 7,  r8 = l >> 3;          // k-slice, row-in-octet-group

    for (int p = 0; p < 8; ++p) {                // 8 passes x 4 waves x 8 rows = 256 rows/block
        const int  rg  = p * 4 + w;              // 0..31
        const long row = (long)blockIdx.x * 256 + rg * 8 + r8;
        const float* xr = x + row * IDIM;

        f32x2 acc[MIXD];
        #pragma unroll
        for (int m = 0; m < MIXD; ++m) acc[m] = (f32x2){0.f, 0.f};

        #pragma unroll
        for (int c = 0; c < 16; ++c) {
            const f32x4 xc = *(const f32x4*)(xr + 4 * (s + 8 * c));  // coalesced
            #pragma unroll
            for (int m = 0; m < MIXD; ++m) {
                const f32x4 wv = *(const f32x4*)(&sw[m][4 * (s + 8 * c)]);
                acc[m] = __builtin_elementwise_fma(xc.xy, wv.xy, acc[m]);
                acc[m] = __builtin_elementwise_fma(xc.zw, wv.zw, acc[m]);
            }
        }
        float zr[MIXD];
        #pragma unroll
        for (int m = 0; m < MIXD; ++m)
            zr[m] = octet_reduce_lane0(acc[m].x + acc[m].y);
        if (s == 0) {
            float* zp = z + row * MIXD;
            #pragma unroll
            for (int mc = 0; mc < 8; ++mc) {
                f32x4 o4 = { zr[mc*4], zr[mc*4+1], zr[mc*4+2], zr[mc*4+3] };
                *(f32x4*)(zp + mc * 4) = o4;
            }
        }
    }
}

// ---------------- K2: GRU scan + head, 1 batch element per block ------------
// 768 threads = 12 waves (3/SIMD). Octet (8 lanes) per h-index j computes all
// three gates with an 8-way k-split, DPP-reduced to lane 0. Weights live in
// registers as float2 (pk_fma candidates), pre-scaled by log2e / 2*log2e so
// activations use raw exp2. One barrier per step, zero global ops in the loop.
__global__ __launch_bounds__(768) void k_scan(const float* __restrict__ z,
                                              const float* __restrict__ Wih,
                                              const float* __restrict__ Whh,
                                              const float* __restrict__ bih,
                                              const float* __restrict__ bhh,
                                              const float* __restrict__ Whead,
                                              const float* __restrict__ bhead,
                                              const float* __restrict__ Wmix,
                                              float* __restrict__ y) {
    const int b   = blockIdx.x;
    const int tid = threadIdx.x;
    const int j   = tid >> 3;     // 0..95
    const int o   = tid & 7;      // 0..7
    const float L  = 1.4426950408889634f;   // log2(e)
    const float L2 = 2.8853900817779268f;   // 2*log2(e)

    __shared__ __align__(16) float sz[256 * MIXD];   // 32 KB: half of the z row
    __shared__ __align__(16) float shp[2][HID];      // h ping-pong
    __shared__ __align__(16) float szn[MIXD];

    // ---- weights into registers as float2, pre-scaled ----
    f32x2 whr[6], whu[6], whn[6], wir[2], wiu[2], win[2];
    #pragma unroll
    for (int c = 0; c < 3; ++c) {
        f32x4 v = *(const f32x4*)(Whh + (size_t)(j        ) * HID + o * 12 + c * 4);
        v *= L;  whr[2*c] = v.xy; whr[2*c+1] = v.zw;
    }
    #pragma unroll
    for (int c = 0; c < 3; ++c) {
        f32x4 v = *(const f32x4*)(Whh + (size_t)(j +   HID) * HID + o * 12 + c * 4);
        v *= L;  whu[2*c] = v.xy; whu[2*c+1] = v.zw;
    }
    #pragma unroll
    for (int c = 0; c < 3; ++c) {
        f32x4 v = *(const f32x4*)(Whh + (size_t)(j + 2*HID) * HID + o * 12 + c * 4);
        v *= L2; whn[2*c] = v.xy; whn[2*c+1] = v.zw;
    }
    {
        f32x4 v = *(const f32x4*)(Wih + (size_t)(j        ) * MIXD + o * 4);
        v *= L;  wir[0] = v.xy; wir[1] = v.zw;
    }
    {
        f32x4 v = *(const f32x4*)(Wih + (size_t)(j +   HID) * MIXD + o * 4);
        v *= L;  wiu[0] = v.xy; wiu[1] = v.zw;
    }
    {
        f32x4 v = *(const f32x4*)(Wih + (size_t)(j + 2*HID) * MIXD + o * 4);
        v *= L2; win[0] = v.xy; win[1] = v.zw;
    }
    float br = 0.f, bu = 0.f, bxn = 0.f, bhn = 0.f;
    if (o == 0) {   // biases contribute once per octet (lane 0), pre-scaled
        br  = L  * (bih[j]       + bhh[j]);
        bu  = L  * (bih[j + HID] + bhh[j + HID]);
        bxn = L2 * bih[j + 2*HID];
        bhn = L2 * bhh[j + 2*HID];
    }

    if (tid < HID) shp[0][tid] = 0.f;   // h0 = 0 (covered by stage barrier)

    const f32x4* zb4 = (const f32x4*)(z + (size_t)b * TT * MIXD);
    f32x4* sz4 = (f32x4*)sz;

    for (int c = 0; c < TT / 256; ++c) {
        for (int idx = tid; idx < 2048; idx += 768)
            sz4[idx] = zb4[c * 2048 + idx];
        __syncthreads();

        #pragma unroll 2
        for (int tt = 0; tt < 256; ++tt) {
            const int t = (c << 8) + tt;
            const float* hr = shp[t & 1];
            float*       hw = shp[(t + 1) & 1];
            const float* zrow = sz + tt * MIXD;

            // all LDS loads issued up front
            const f32x4 z4 = *(const f32x4*)(zrow + o * 4);
            const f32x4 h0 = *(const f32x4*)(hr + o * 12);
            const f32x4 h1 = *(const f32x4*)(hr + o * 12 + 4);
            const f32x4 h2 = *(const f32x4*)(hr + o * 12 + 8);
            const float hold = hr[j];

            // accumulators (biases folded into lane-0 init)
            f32x2 aR  = {br,  0.f}, aU  = {bu,  0.f};
            f32x2 aXN = {bxn, 0.f}, aHN = {bhn, 0.f};

            // ih-part (z): 2 f32x2 chunks per gate
            aR  = __builtin_elementwise_fma(wir[0], z4.xy, aR);
            aR  = __builtin_elementwise_fma(wir[1], z4.zw, aR);
            aU  = __builtin_elementwise_fma(wiu[0], z4.xy, aU);
            aU  = __builtin_elementwise_fma(wiu[1], z4.zw, aU);
            aXN = __builtin_elementwise_fma(win[0], z4.xy, aXN);
            aXN = __builtin_elementwise_fma(win[1], z4.zw, aXN);

            // hh-part (h): 6 f32x2 chunks per gate
            const f32x2 hh[6] = { h0.xy, h0.zw, h1.xy, h1.zw, h2.xy, h2.zw };
            #pragma unroll
            for (int k = 0; k < 6; ++k) {
                aR  = __builtin_elementwise_fma(whr[k], hh[k], aR);
                aU  = __builtin_elementwise_fma(whu[k], hh[k], aU);
                aHN = __builtin_elementwise_fma(whn[k], hh[k], aHN);
            }

            // horizontal + octet DPP reduce (result valid on lane o==0)
            float sR  = octet_reduce_lane0(aR.x  + aR.y);
            float sU  = octet_reduce_lane0(aU.x  + aU.y);
            float sXN = octet_reduce_lane0(aXN.x + aXN.y);
            float sHN = octet_reduce_lane0(aHN.x + aHN.y);

            // activations via raw exp2 (scales folded into weights)
            float r = __builtin_amdgcn_rcpf(1.f + EXP2(-sR));
            float u = __builtin_amdgcn_rcpf(1.f + EXP2(-sU));
            float n = 1.f - 2.f * __builtin_amdgcn_rcpf(1.f + EXP2(sXN + r * sHN));
            float hnew = u * (hold - n) + n;    // (1-u)*n + u*h
            if (o == 0) hw[j] = hnew;
            __syncthreads();                    // the ONLY barrier per step
        }
    }

    // ---- fused head: zn = Whead @ h + bhead ; y = zn @ Wmix ----
    if (tid < MIXD) {
        const float* h = shp[0];                 // TT even -> final h in shp[0]
        float a0 = 0.f, a1 = 0.f, a2 = 0.f, a3 = 0.f;
        #pragma unroll
        for (int kc = 0; kc < HID / 4; ++kc) {
            f32x4 wv = *(const f32x4*)(Whead + (size_t)tid * HID + kc * 4);
            f32x4 hv = *(const f32x4*)(h + kc * 4);
            a0 += wv.x * hv.x; a1 += wv.y * hv.y;
            a2 += wv.z * hv.z; a3 += wv.w * hv.w;
        }
        szn[tid] = bhead[tid] + ((a0 + a1) + (a2 + a3));
    }
    __syncthreads();
    if (tid < IDIM) {
        float acc = 0.f;
        #pragma unroll
        for (int m = 0; m < MIXD; ++m)
            acc += szn[m] * Wmix[(size_t)m * IDIM + tid];
        y[(size_t)b * IDIM + tid] = acc;
    }
}

extern "C" void kernel_launch(void* const* d_in, const int* in_sizes, int n_in,
                              void* d_out, int out_size, void* d_ws, size_t ws_size,
                              hipStream_t stream) {
    const float* x     = (const float*)d_in[0];
    const float* Wmix  = (const float*)d_in[1];
    const float* Wih   = (const float*)d_in[2];
    const float* Whh   = (const float*)d_in[3];
    const float* bih   = (const float*)d_in[4];
    const float* bhh   = (const float*)d_in[5];
    const float* Whead = (const float*)d_in[6];
    const float* bhead = (const float*)d_in[7];
    float* out = (float*)d_out;

    float* z = (float*)d_ws;   // [B*T, 32] = 16.78 MB

    k_mix <<<512, 256, 0, stream>>>(x, Wmix, z);
    k_scan<<<BB,  768, 0, stream>>>(z, Wih, Whh, bih, bhh, Whead, bhead, Wmix, out);
}

// Round 7
// 419.245 us; speedup vs baseline: 4.8785x; 4.8785x over previous
//
#include <hip/hip_runtime.h>

#define IDIM 512
#define MIXD 32
#define HID 96
#define BB 256
#define TT 512

typedef float f32x2 __attribute__((ext_vector_type(2)));
typedef float f32x4 __attribute__((ext_vector_type(4)));

// v_exp_f32: D = 2^S0
#define EXP2(x) __builtin_amdgcn_exp2f(x)

// DPP row_shl:N add on the VALU pipe (not the shared LDS pipe).
// dpp_ctrl must be an ICE at the call site -> template parameter.
template <int CTRL>
__device__ __forceinline__ float dpp_shl_add(float x) {
    int m = __builtin_amdgcn_update_dpp(0, __float_as_int(x), CTRL, 0xf, 0xf, true);
    return x + __int_as_float(m);
}
// Reduce 8 consecutive lanes (octet) into the octet's lane 0.
__device__ __forceinline__ float octet_reduce_lane0(float x) {
    x = dpp_shl_add<0x104>(x);   // row_shl:4
    x = dpp_shl_add<0x102>(x);   // row_shl:2
    x = dpp_shl_add<0x101>(x);   // row_shl:1
    return x;
}

// ---------------- K1: z = x @ W_mix^T -----------------------------------
// Memory-bound (268 MB x-read; floor 43 us). One ROW PER THREAD (no reduce,
// no divergence), but x is staged through LDS so the global reads coalesce:
// 32-col chunks, double-buffered [256][36] tile (pad 36 -> even 8-words/bank
// b128 distribution). Next chunk's global loads issue before compute so HBM
// latency hides under the FMAs. W is read at wave-uniform addresses ->
// s_load through the scalar cache (no VGPR, no LDS), as f32x2 pairs feeding
// v_pk_fma_f32. Register budget: acc 64 + stage 32 + row 32 -> ~150 VGPR,
// no spills (R6 failure mode: 256 VGPR + 433 MB spill writes).
#define KC 32
#define SROW 36   // LDS row stride in floats
__global__ __launch_bounds__(256, 2) void k_mix(const float* __restrict__ x,
                                                const float* __restrict__ Wmix,
                                                float* __restrict__ z) {
    __shared__ __align__(16) float sx[2][256 * SROW];   // 2 x 36 KB
    const int tid = threadIdx.x;
    const long base = (long)blockIdx.x * 256;
    const float* xb = x + base * IDIM;

    f32x4 st[8];
    // ---- prologue: chunk 0 -> LDS buf0; chunk 1 -> regs ----
    #pragma unroll
    for (int i = 0; i < 8; ++i) {
        const int v = tid + 256 * i, r = v >> 3, q = v & 7;
        st[i] = *(const f32x4*)(xb + (long)r * IDIM + q * 4);         // cols 0..31
    }
    #pragma unroll
    for (int i = 0; i < 8; ++i) {
        const int v = tid + 256 * i, r = v >> 3, q = v & 7;
        *(f32x4*)(&sx[0][r * SROW + q * 4]) = st[i];
    }
    #pragma unroll
    for (int i = 0; i < 8; ++i) {
        const int v = tid + 256 * i, r = v >> 3, q = v & 7;
        st[i] = *(const f32x4*)(xb + (long)r * IDIM + KC + q * 4);    // cols 32..63
    }
    __syncthreads();

    f32x2 acc[MIXD];
    #pragma unroll
    for (int m = 0; m < MIXD; ++m) acc[m] = (f32x2){0.f, 0.f};

    for (int c = 0; c < IDIM / KC; ++c) {                 // 16 chunks
        // stage chunk c+1 (regs -> LDS); reads of this buffer finished at the
        // barrier ending iter c-1
        if (c + 1 < IDIM / KC) {
            #pragma unroll
            for (int i = 0; i < 8; ++i) {
                const int v = tid + 256 * i, r = v >> 3, q = v & 7;
                *(f32x4*)(&sx[(c + 1) & 1][r * SROW + q * 4]) = st[i];
            }
        }
        // issue chunk c+2 global loads (latency hides under compute)
        if (c + 2 < IDIM / KC) {
            #pragma unroll
            for (int i = 0; i < 8; ++i) {
                const int v = tid + 256 * i, r = v >> 3, q = v & 7;
                st[i] = *(const f32x4*)(xb + (long)r * IDIM + (c + 2) * KC + q * 4);
            }
        }
        // compute chunk c: own row from LDS, W via uniform s_load pairs
        const float* rp = &sx[c & 1][tid * SROW];
        f32x4 xr[8];
        #pragma unroll
        for (int i = 0; i < 8; ++i) xr[i] = *(const f32x4*)(rp + i * 4);
        const float* wc = Wmix + c * KC;
        #pragma unroll
        for (int kp = 0; kp < KC / 2; ++kp) {
            const f32x2 xp = (kp & 1) ? xr[kp >> 1].zw : xr[kp >> 1].xy;
            #pragma unroll
            for (int m = 0; m < MIXD; ++m) {
                const f32x2 wp = *(const f32x2*)(wc + (size_t)m * IDIM + kp * 2); // uniform
                acc[m] = __builtin_elementwise_fma(wp, xp, acc[m]);
            }
        }
        __syncthreads();
    }

    float* zp = z + (base + tid) * MIXD;
    #pragma unroll
    for (int mc = 0; mc < 8; ++mc) {
        f32x4 o4 = { acc[mc*4].x   + acc[mc*4].y,
                     acc[mc*4+1].x + acc[mc*4+1].y,
                     acc[mc*4+2].x + acc[mc*4+2].y,
                     acc[mc*4+3].x + acc[mc*4+3].y };
        *(f32x4*)(zp + mc * 4) = o4;
    }
}

// ---------------- K2: GRU scan + head, 1 batch element per block ------------
// 768 threads = 12 waves (3/SIMD). Octet (8 lanes) per h-index j computes all
// three gates with an 8-way k-split, DPP-reduced to lane 0. Weights live in
// registers as float2 (pk_fma candidates), pre-scaled by log2e / 2*log2e so
// activations use raw exp2. One barrier per step, zero global ops in the loop.
__global__ __launch_bounds__(768) void k_scan(const float* __restrict__ z,
                                              const float* __restrict__ Wih,
                                              const float* __restrict__ Whh,
                                              const float* __restrict__ bih,
                                              const float* __restrict__ bhh,
                                              const float* __restrict__ Whead,
                                              const float* __restrict__ bhead,
                                              const float* __restrict__ Wmix,
                                              float* __restrict__ y) {
    const int b   = blockIdx.x;
    const int tid = threadIdx.x;
    const int j   = tid >> 3;     // 0..95
    const int o   = tid & 7;      // 0..7
    const float L  = 1.4426950408889634f;   // log2(e)
    const float L2 = 2.8853900817779268f;   // 2*log2(e)

    __shared__ __align__(16) float sz[256 * MIXD];   // 32 KB: half of the z row
    __shared__ __align__(16) float shp[2][HID];      // h ping-pong
    __shared__ __align__(16) float szn[MIXD];

    // ---- weights into registers as float2, pre-scaled ----
    f32x2 whr[6], whu[6], whn[6], wir[2], wiu[2], win[2];
    #pragma unroll
    for (int c = 0; c < 3; ++c) {
        f32x4 v = *(const f32x4*)(Whh + (size_t)(j        ) * HID + o * 12 + c * 4);
        v *= L;  whr[2*c] = v.xy; whr[2*c+1] = v.zw;
    }
    #pragma unroll
    for (int c = 0; c < 3; ++c) {
        f32x4 v = *(const f32x4*)(Whh + (size_t)(j +   HID) * HID + o * 12 + c * 4);
        v *= L;  whu[2*c] = v.xy; whu[2*c+1] = v.zw;
    }
    #pragma unroll
    for (int c = 0; c < 3; ++c) {
        f32x4 v = *(const f32x4*)(Whh + (size_t)(j + 2*HID) * HID + o * 12 + c * 4);
        v *= L2; whn[2*c] = v.xy; whn[2*c+1] = v.zw;
    }
    {
        f32x4 v = *(const f32x4*)(Wih + (size_t)(j        ) * MIXD + o * 4);
        v *= L;  wir[0] = v.xy; wir[1] = v.zw;
    }
    {
        f32x4 v = *(const f32x4*)(Wih + (size_t)(j +   HID) * MIXD + o * 4);
        v *= L;  wiu[0] = v.xy; wiu[1] = v.zw;
    }
    {
        f32x4 v = *(const f32x4*)(Wih + (size_t)(j + 2*HID) * MIXD + o * 4);
        v *= L2; win[0] = v.xy; win[1] = v.zw;
    }
    float br = 0.f, bu = 0.f, bxn = 0.f, bhn = 0.f;
    if (o == 0) {   // biases contribute once per octet (lane 0), pre-scaled
        br  = L  * (bih[j]       + bhh[j]);
        bu  = L  * (bih[j + HID] + bhh[j + HID]);
        bxn = L2 * bih[j + 2*HID];
        bhn = L2 * bhh[j + 2*HID];
    }

    if (tid < HID) shp[0][tid] = 0.f;   // h0 = 0 (covered by stage barrier)

    const f32x4* zb4 = (const f32x4*)(z + (size_t)b * TT * MIXD);
    f32x4* sz4 = (f32x4*)sz;

    for (int c = 0; c < TT / 256; ++c) {
        for (int idx = tid; idx < 2048; idx += 768)
            sz4[idx] = zb4[c * 2048 + idx];
        __syncthreads();

        #pragma unroll 2
        for (int tt = 0; tt < 256; ++tt) {
            const int t = (c << 8) + tt;
            const float* hr = shp[t & 1];
            float*       hw = shp[(t + 1) & 1];
            const float* zrow = sz + tt * MIXD;

            // all LDS loads issued up front
            const f32x4 z4 = *(const f32x4*)(zrow + o * 4);
            const f32x4 h0 = *(const f32x4*)(hr + o * 12);
            const f32x4 h1 = *(const f32x4*)(hr + o * 12 + 4);
            const f32x4 h2 = *(const f32x4*)(hr + o * 12 + 8);
            const float hold = hr[j];

            // accumulators (biases folded into lane-0 init)
            f32x2 aR  = {br,  0.f}, aU  = {bu,  0.f};
            f32x2 aXN = {bxn, 0.f}, aHN = {bhn, 0.f};

            // ih-part (z): 2 f32x2 chunks per gate
            aR  = __builtin_elementwise_fma(wir[0], z4.xy, aR);
            aR  = __builtin_elementwise_fma(wir[1], z4.zw, aR);
            aU  = __builtin_elementwise_fma(wiu[0], z4.xy, aU);
            aU  = __builtin_elementwise_fma(wiu[1], z4.zw, aU);
            aXN = __builtin_elementwise_fma(win[0], z4.xy, aXN);
            aXN = __builtin_elementwise_fma(win[1], z4.zw, aXN);

            // hh-part (h): 6 f32x2 chunks per gate
            const f32x2 hh[6] = { h0.xy, h0.zw, h1.xy, h1.zw, h2.xy, h2.zw };
            #pragma unroll
            for (int k = 0; k < 6; ++k) {
                aR  = __builtin_elementwise_fma(whr[k], hh[k], aR);
                aU  = __builtin_elementwise_fma(whu[k], hh[k], aU);
                aHN = __builtin_elementwise_fma(whn[k], hh[k], aHN);
            }

            // horizontal + octet DPP reduce (result valid on lane o==0)
            float sR  = octet_reduce_lane0(aR.x  + aR.y);
            float sU  = octet_reduce_lane0(aU.x  + aU.y);
            float sXN = octet_reduce_lane0(aXN.x + aXN.y);
            float sHN = octet_reduce_lane0(aHN.x + aHN.y);

            // activations via raw exp2 (scales folded into weights)
            float r = __builtin_amdgcn_rcpf(1.f + EXP2(-sR));
            float u = __builtin_amdgcn_rcpf(1.f + EXP2(-sU));
            float n = 1.f - 2.f * __builtin_amdgcn_rcpf(1.f + EXP2(sXN + r * sHN));
            float hnew = u * (hold - n) + n;    // (1-u)*n + u*h
            if (o == 0) hw[j] = hnew;
            __syncthreads();                    // the ONLY barrier per step
        }
    }

    // ---- fused head: zn = Whead @ h + bhead ; y = zn @ Wmix ----
    if (tid < MIXD) {
        const float* h = shp[0];                 // TT even -> final h in shp[0]
        float a0 = 0.f, a1 = 0.f, a2 = 0.f, a3 = 0.f;
        #pragma unroll
        for (int kc = 0; kc < HID / 4; ++kc) {
            f32x4 wv = *(const f32x4*)(Whead + (size_t)tid * HID + kc * 4);
            f32x4 hv = *(const f32x4*)(h + kc * 4);
            a0 += wv.x * hv.x; a1 += wv.y * hv.y;
            a2 += wv.z * hv.z; a3 += wv.w * hv.w;
        }
        szn[tid] = bhead[tid] + ((a0 + a1) + (a2 + a3));
    }
    __syncthreads();
    if (tid < IDIM) {
        float acc = 0.f;
        #pragma unroll
        for (int m = 0; m < MIXD; ++m)
            acc += szn[m] * Wmix[(size_t)m * IDIM + tid];
        y[(size_t)b * IDIM + tid] = acc;
    }
}

extern "C" void kernel_launch(void* const* d_in, const int* in_sizes, int n_in,
                              void* d_out, int out_size, void* d_ws, size_t ws_size,
                              hipStream_t stream) {
    const float* x     = (const float*)d_in[0];
    const float* Wmix  = (const float*)d_in[1];
    const float* Wih   = (const float*)d_in[2];
    const float* Whh   = (const float*)d_in[3];
    const float* bih   = (const float*)d_in[4];
    const float* bhh   = (const float*)d_in[5];
    const float* Whead = (const float*)d_in[6];
    const float* bhead = (const float*)d_in[7];
    float* out = (float*)d_out;

    float* z = (float*)d_ws;   // [B*T, 32] = 16.78 MB

    k_mix <<<512, 256, 0, stream>>>(x, Wmix, z);
    k_scan<<<BB,  768, 0, stream>>>(z, Wih, Whh, bih, bhh, Whead, bhead, Wmix, out);
}